// Round 1
// baseline (115.919 us; speedup 1.0000x reference)
//
#include <hip/hip_runtime.h>
#include <hip/hip_bf16.h>

typedef __bf16 bf16x8 __attribute__((ext_vector_type(8)));
typedef float f32x4 __attribute__((ext_vector_type(4)));

#define N_IMG 32
#define C_IN 128
#define HW 56
#define PIX 3136            // 56*56
#define NPLANE 401408       // 128*3136
#define APAD_ROWSTRIDE 7424 // 58*128
#define APAD_NSTRIDE 430592 // 58*58*128

// ---------------- BN partial stats: grid (128 c, 8 slices) ----------------
__global__ __launch_bounds__(256) void bn_partial_k(const float* __restrict__ x,
                                                    double* __restrict__ part) {
  const int c = blockIdx.x, sl = blockIdx.y;
  const int tid = threadIdx.x;
  double s = 0.0, s2 = 0.0;
  for (int n = sl * 4; n < sl * 4 + 4; ++n) {
    const float4* p = (const float4*)(x + (size_t)(n * C_IN + c) * PIX);
    for (int i = tid; i < PIX / 4; i += 256) {
      float4 v = p[i];
      s  += (double)v.x + (double)v.y + (double)v.z + (double)v.w;
      s2 += (double)v.x * v.x + (double)v.y * v.y + (double)v.z * v.z + (double)v.w * v.w;
    }
  }
  __shared__ double red[8];
  const int lane = tid & 63, wv = tid >> 6;
  for (int off = 32; off; off >>= 1) { s += __shfl_down(s, off); s2 += __shfl_down(s2, off); }
  if (lane == 0) { red[wv * 2] = s; red[wv * 2 + 1] = s2; }
  __syncthreads();
  if (tid == 0) {
    s = red[0] + red[2] + red[4] + red[6];
    s2 = red[1] + red[3] + red[5] + red[7];
    part[(c * 8 + sl) * 2] = s;
    part[(c * 8 + sl) * 2 + 1] = s2;
  }
}

// ---------------- weight partial stats: 64 blocks over 36864 float4 ----------------
__global__ __launch_bounds__(256) void w_partial_k(const float* __restrict__ w,
                                                   double* __restrict__ part) {
  const int b = blockIdx.x, tid = threadIdx.x;
  double s = 0.0, s2 = 0.0;
  const float4* p = (const float4*)w;
  for (int i = b * 576 + tid; i < (b + 1) * 576; i += 256) {
    float4 v = p[i];
    s  += (double)v.x + (double)v.y + (double)v.z + (double)v.w;
    s2 += (double)v.x * v.x + (double)v.y * v.y + (double)v.z * v.z + (double)v.w * v.w;
  }
  __shared__ double red[8];
  const int lane = tid & 63, wv = tid >> 6;
  for (int off = 32; off; off >>= 1) { s += __shfl_down(s, off); s2 += __shfl_down(s2, off); }
  if (lane == 0) { red[wv * 2] = s; red[wv * 2 + 1] = s2; }
  __syncthreads();
  if (tid == 0) {
    part[b * 2] = red[0] + red[2] + red[4] + red[6];
    part[b * 2 + 1] = red[1] + red[3] + red[5] + red[7];
  }
}

// ---------------- finalize: per-channel affine + weight step ----------------
__global__ __launch_bounds__(256) void finalize_k(const double* __restrict__ bnpart,
                                                  const double* __restrict__ wpart,
                                                  const float* __restrict__ gamma,
                                                  const float* __restrict__ beta,
                                                  float2* __restrict__ affine,
                                                  float* __restrict__ stepp) {
  const int tid = threadIdx.x;
  if (tid < 128) {
    double s = 0.0, s2 = 0.0;
    for (int i = 0; i < 8; ++i) { s += bnpart[(tid * 8 + i) * 2]; s2 += bnpart[(tid * 8 + i) * 2 + 1]; }
    const double mean = s / 100352.0;
    const double var = s2 / 100352.0 - mean * mean;
    const double inv = 1.0 / sqrt(var + 1e-3);  // BN_EPS
    const float sA = (float)((double)gamma[tid] * inv);
    const float shA = (float)((double)beta[tid] - mean * inv * (double)gamma[tid]);
    affine[tid] = make_float2(sA, shA);
  } else if (tid >= 192) {
    const int l = tid - 192;  // one full wave
    double s = wpart[l * 2], s2 = wpart[l * 2 + 1];
    for (int off = 32; off; off >>= 1) { s += __shfl_down(s, off); s2 += __shfl_down(s2, off); }
    if (l == 0) {
      const double mean = s / 147456.0;
      const double var = s2 / 147456.0 - mean * mean;
      stepp[0] = 0.996f * (float)sqrt(var);   // GAUSS_STEP * std
    }
  }
}

// ---------------- quantize activations -> padded NHWC bf16 levels ----------------
// grid (58 padded rows, 32 n). Border rows/cols written as zero.
__global__ __launch_bounds__(256) void quant_act_k(const float* __restrict__ x,
                                                   const float2* __restrict__ affine,
                                                   ushort* __restrict__ apad) {
  const int hh = blockIdx.x;  // padded row 0..57
  const int n = blockIdx.y;
  const int tid = threadIdx.x;
  __shared__ __align__(16) ushort lds[58 * 136];  // col-stride 136 (pad) to soften bank conflicts
  uint4* lds4 = (uint4*)lds;
  for (int i = tid; i < 58 * 136 / 8; i += 256) lds4[i] = make_uint4(0, 0, 0, 0);
  __syncthreads();
  if (hh >= 1 && hh <= 56) {
    const int h = hh - 1;
    const float* xp = x + (size_t)n * NPLANE + h * HW;
    for (int i = tid; i < C_IN * HW; i += 256) {
      const int w = i % HW, c = i / HW;
      const float v = xp[(size_t)c * PIX + w];
      const float2 af = affine[c];
      const float xn = fmaf(v, af.x, af.y);
      const float y = fminf(fmaxf(xn, 0.f), 1.614f);     // clip to [0, 3*0.538]
      const float fia = rintf(y / 0.538f);               // level 0..3 (round-half-even)
      lds[(w + 1) * 136 + c] = (ushort)(__float_as_uint(fia) >> 16);  // exact bf16
    }
  }
  __syncthreads();
  uint4* dst = (uint4*)(apad + (size_t)n * APAD_NSTRIDE + (size_t)hh * APAD_ROWSTRIDE);
  for (int i = tid; i < 58 * 16; i += 256) {   // 58 cols * 16 uint4 (128 ch)
    const int col = i >> 4, c16 = i & 15;
    dst[i] = lds4[col * 17 + c16];
  }
}

// ---------------- quantize weights -> Wq[(rs*2+cc)][128 oc][64 c] bf16 (iw2 levels) ----------------
__global__ __launch_bounds__(256) void quant_w_k(const float* __restrict__ w,
                                                 const float* __restrict__ stepp,
                                                 ushort* __restrict__ wq) {
  const int oc = blockIdx.x, tid = threadIdx.x;
  const float step = stepp[0];
  __shared__ __align__(16) ushort lds[9 * 128];
  for (int i = tid; i < 1152; i += 256) {
    const int c = i / 9, rs = i % 9;
    const float v = w[(size_t)(oc * C_IN + c) * 9 + rs];
    float t = 2.f * rintf(v / step + 0.5f) - 1.f;   // iw2 = 2*q/step, odd ints
    t = fminf(fmaxf(t, -3.f), 3.f);
    lds[rs * 128 + c] = (ushort)(__float_as_uint(t) >> 16);  // exact bf16
  }
  __syncthreads();
  uint4* wq4 = (uint4*)wq;
  const uint4* lds4 = (const uint4*)lds;
  for (int i = tid; i < 144; i += 256) {       // 18 chunks * 8 uint4
    const int chunk = i >> 3, within = i & 7;  // chunk = rs*2+cc
    wq4[(chunk * 128 + oc) * 8 + within] = lds4[i];
  }
}

// ---------------- conv: block = (row-pair, n); 128 oc x 112 px; 4 waves ----------------
__global__ __launch_bounds__(256) void conv_k(const ushort* __restrict__ apad,
                                              const ushort* __restrict__ wq,
                                              const float* __restrict__ stepp,
                                              float* __restrict__ out) {
  __shared__ __align__(16) ushort Alds[4 * 58 * 72];  // 4 rows x 58 cols x 64c, px-stride 72 (pad)
  __shared__ __align__(16) ushort Wlds[128 * 72];     // 128 oc x 64c, oc-stride 72 (pad)
  const int rp = blockIdx.x, n = blockIdx.y;
  const int h0 = rp * 2;
  const int tid = threadIdx.x;
  const int wv = tid >> 6, lane = tid & 63;
  const int lr = lane & 15, q4 = lane >> 4;
  const int hi8 = q4 * 8;
  const int ocb = wv * 32;
  f32x4 acc[7][2];
#pragma unroll
  for (int i = 0; i < 7; ++i)
#pragma unroll
    for (int j = 0; j < 2; ++j) acc[i][j] = (f32x4){0.f, 0.f, 0.f, 0.f};
  int prow[7], pcol[7];
#pragma unroll
  for (int pf = 0; pf < 7; ++pf) {
    const int p = pf * 16 + lr;
    prow[pf] = p / 56;
    pcol[pf] = p - 56 * prow[pf];
  }
  const ushort* apn = apad + (size_t)n * APAD_NSTRIDE + (size_t)h0 * APAD_ROWSTRIDE;

  for (int cc = 0; cc < 2; ++cc) {
    __syncthreads();  // previous-iteration Alds readers done
    // stage act: 4 rows x 58 cols x 64 ch = 1856 x 16B units
    for (int wc = wv; wc < 29; wc += 4) {
      const int u = wc * 64 + lane;
      const int pxl = u >> 3, c16 = u & 7;
      *(uint4*)&Alds[pxl * 72 + c16 * 8] = *(const uint4*)&apn[pxl * 128 + cc * 64 + c16 * 8];
    }
    for (int rs = 0; rs < 9; ++rs) {
      __syncthreads();  // previous Wlds readers done (+ Alds writes visible at rs==0)
      {
        const int base = (rs * 2 + cc) * 8192;
        for (int wc = wv; wc < 16; wc += 4) {
          const int u = wc * 64 + lane;
          const int oc = u >> 3, c16 = u & 7;
          *(uint4*)&Wlds[oc * 72 + c16 * 8] = *(const uint4*)&wq[base + u * 8];
        }
      }
      __syncthreads();  // Wlds ready
      const int r = rs / 3, s = rs - 3 * (rs / 3);
      bf16x8 wf[2][2];
#pragma unroll
      for (int of = 0; of < 2; ++of)
#pragma unroll
        for (int kk = 0; kk < 2; ++kk)
          wf[of][kk] = *(const bf16x8*)&Wlds[(ocb + of * 16 + lr) * 72 + kk * 32 + hi8];
#pragma unroll
      for (int pf = 0; pf < 7; ++pf) {
        const int base = ((prow[pf] + r) * 58 + pcol[pf] + s) * 72 + hi8;
        const bf16x8 b0 = *(const bf16x8*)&Alds[base];
        const bf16x8 b1 = *(const bf16x8*)&Alds[base + 32];
        acc[pf][0] = __builtin_amdgcn_mfma_f32_16x16x32_bf16(wf[0][0], b0, acc[pf][0], 0, 0, 0);
        acc[pf][1] = __builtin_amdgcn_mfma_f32_16x16x32_bf16(wf[1][0], b0, acc[pf][1], 0, 0, 0);
        acc[pf][0] = __builtin_amdgcn_mfma_f32_16x16x32_bf16(wf[0][1], b1, acc[pf][0], 0, 0, 0);
        acc[pf][1] = __builtin_amdgcn_mfma_f32_16x16x32_bf16(wf[1][1], b1, acc[pf][1], 0, 0, 0);
      }
    }
  }

  const float oscale = 0.5f * 0.538f * stepp[0];  // a_step * w_step/2
  float* outn = out + (size_t)n * NPLANE + h0 * HW;
#pragma unroll
  for (int pf = 0; pf < 7; ++pf)
#pragma unroll
    for (int of = 0; of < 2; ++of)
#pragma unroll
      for (int q = 0; q < 4; ++q) {
        const int oc = ocb + of * 16 + q4 * 4 + q;
        outn[(size_t)oc * PIX + pf * 16 + lr] = acc[pf][of][q] * oscale;
      }
}

extern "C" void kernel_launch(void* const* d_in, const int* in_sizes, int n_in,
                              void* d_out, int out_size, void* d_ws, size_t ws_size,
                              hipStream_t stream) {
  const float* x = (const float*)d_in[0];
  const float* gamma = (const float*)d_in[1];
  const float* beta = (const float*)d_in[2];
  const float* w = (const float*)d_in[3];
  float* out = (float*)d_out;
  char* ws = (char*)d_ws;

  double* bnpart = (double*)(ws);            // 128*8*2*8 = 16384 B
  double* wpart = (double*)(ws + 16384);     // 64*2*8   = 1024 B
  float2* affine = (float2*)(ws + 17408);    // 128*8    = 1024 B
  float* stepp = (float*)(ws + 18432);       // 4 B
  ushort* wq = (ushort*)(ws + 18688);        // 18*128*64*2 = 294912 B -> ends 313600
  ushort* apad = (ushort*)(ws + 327680);     // 32*58*58*128*2 = 27557888 B

  bn_partial_k<<<dim3(128, 8), 256, 0, stream>>>(x, bnpart);
  w_partial_k<<<64, 256, 0, stream>>>(w, wpart);
  finalize_k<<<1, 256, 0, stream>>>(bnpart, wpart, gamma, beta, affine, stepp);
  quant_act_k<<<dim3(58, 32), 256, 0, stream>>>(x, affine, apad);
  quant_w_k<<<128, 256, 0, stream>>>(w, stepp, wq);
  conv_k<<<dim3(28, 32), 256, 0, stream>>>(apad, wq, stepp, out);
}

// Round 2
// 77.528 us; speedup vs baseline: 1.4952x; 1.4952x over previous
//
#include <hip/hip_runtime.h>
#include <hip/hip_bf16.h>

typedef int i32x4 __attribute__((ext_vector_type(4)));

#define N_IMG 32
#define C_IN 128
#define HW 56
#define PIX 3136            // 56*56
#define NPLANE 401408       // 128*3136
#define APAD_ROWSTRIDE 7424 // 58*128 (bytes, i8)
#define APAD_NSTRIDE 430592 // 58*58*128

// ---------------- BN partial stats: grid (128 c, 8 slices) ----------------
__global__ __launch_bounds__(256) void bn_partial_k(const float* __restrict__ x,
                                                    double* __restrict__ part) {
  const int c = blockIdx.x, sl = blockIdx.y;
  const int tid = threadIdx.x;
  double s = 0.0, s2 = 0.0;
  for (int n = sl * 4; n < sl * 4 + 4; ++n) {
    const float4* p = (const float4*)(x + (size_t)(n * C_IN + c) * PIX);
    for (int i = tid; i < PIX / 4; i += 256) {
      float4 v = p[i];
      s  += (double)v.x + (double)v.y + (double)v.z + (double)v.w;
      s2 += (double)v.x * v.x + (double)v.y * v.y + (double)v.z * v.z + (double)v.w * v.w;
    }
  }
  __shared__ double red[8];
  const int lane = tid & 63, wv = tid >> 6;
  for (int off = 32; off; off >>= 1) { s += __shfl_down(s, off); s2 += __shfl_down(s2, off); }
  if (lane == 0) { red[wv * 2] = s; red[wv * 2 + 1] = s2; }
  __syncthreads();
  if (tid == 0) {
    s = red[0] + red[2] + red[4] + red[6];
    s2 = red[1] + red[3] + red[5] + red[7];
    part[(c * 8 + sl) * 2] = s;
    part[(c * 8 + sl) * 2 + 1] = s2;
  }
}

// ---------------- weight partial stats ----------------
__global__ __launch_bounds__(256) void w_partial_k(const float* __restrict__ w,
                                                   double* __restrict__ part) {
  const int b = blockIdx.x, tid = threadIdx.x;
  double s = 0.0, s2 = 0.0;
  const float4* p = (const float4*)w;
  for (int i = b * 576 + tid; i < (b + 1) * 576; i += 256) {
    float4 v = p[i];
    s  += (double)v.x + (double)v.y + (double)v.z + (double)v.w;
    s2 += (double)v.x * v.x + (double)v.y * v.y + (double)v.z * v.z + (double)v.w * v.w;
  }
  __shared__ double red[8];
  const int lane = tid & 63, wv = tid >> 6;
  for (int off = 32; off; off >>= 1) { s += __shfl_down(s, off); s2 += __shfl_down(s2, off); }
  if (lane == 0) { red[wv * 2] = s; red[wv * 2 + 1] = s2; }
  __syncthreads();
  if (tid == 0) {
    part[b * 2] = red[0] + red[2] + red[4] + red[6];
    part[b * 2 + 1] = red[1] + red[3] + red[5] + red[7];
  }
}

// ---------------- finalize ----------------
__global__ __launch_bounds__(256) void finalize_k(const double* __restrict__ bnpart,
                                                  const double* __restrict__ wpart,
                                                  const float* __restrict__ gamma,
                                                  const float* __restrict__ beta,
                                                  float2* __restrict__ affine,
                                                  float* __restrict__ stepp) {
  const int tid = threadIdx.x;
  if (tid < 128) {
    double s = 0.0, s2 = 0.0;
    for (int i = 0; i < 8; ++i) { s += bnpart[(tid * 8 + i) * 2]; s2 += bnpart[(tid * 8 + i) * 2 + 1]; }
    const double mean = s / 100352.0;
    const double var = s2 / 100352.0 - mean * mean;
    const double inv = 1.0 / sqrt(var + 1e-3);
    const float sA = (float)((double)gamma[tid] * inv);
    const float shA = (float)((double)beta[tid] - mean * inv * (double)gamma[tid]);
    affine[tid] = make_float2(sA, shA);
  } else if (tid >= 192) {
    const int l = tid - 192;
    double s = wpart[l * 2], s2 = wpart[l * 2 + 1];
    for (int off = 32; off; off >>= 1) { s += __shfl_down(s, off); s2 += __shfl_down(s2, off); }
    if (l == 0) {
      const double mean = s / 147456.0;
      const double var = s2 / 147456.0 - mean * mean;
      stepp[0] = 0.996f * (float)sqrt(var);
    }
  }
}

// ---------------- quantize activations -> padded NHWC int8 levels ----------------
__global__ __launch_bounds__(256) void quant_act_k(const float* __restrict__ x,
                                                   const float2* __restrict__ affine,
                                                   signed char* __restrict__ apad) {
  const int hh = blockIdx.x;  // padded row 0..57
  const int n = blockIdx.y;
  const int tid = threadIdx.x;
  __shared__ __align__(16) signed char lds[58 * 144];  // col stride 144 (16B aligned)
  uint4* lds4 = (uint4*)lds;
  for (int i = tid; i < 58 * 144 / 16; i += 256) lds4[i] = make_uint4(0, 0, 0, 0);
  __syncthreads();
  if (hh >= 1 && hh <= 56) {
    const float* xp = x + (size_t)n * NPLANE + (hh - 1) * HW;
    for (int i = tid; i < C_IN * HW; i += 256) {
      const int w = i % HW, c = i / HW;
      const float v = xp[(size_t)c * PIX + w];
      const float2 af = affine[c];
      const float xn = fmaf(v, af.x, af.y);
      const float y = fminf(fmaxf(xn, 0.f), 1.614f);  // clip [0, 3*0.538]
      lds[(w + 1) * 144 + c] = (signed char)(int)rintf(y / 0.538f);  // level 0..3
    }
  }
  __syncthreads();
  uint4* dst = (uint4*)(apad + (size_t)n * APAD_NSTRIDE + (size_t)hh * APAD_ROWSTRIDE);
  for (int i = tid; i < 58 * 8; i += 256) {  // 58 cols * 8 uint4 (128 ch i8)
    const int col = i >> 3, c16 = i & 7;
    dst[i] = lds4[col * 9 + c16];
  }
}

// ---------------- quantize weights -> wq[rs][128 oc][128 c] int8 ----------------
__global__ __launch_bounds__(128) void quant_w_k(const float* __restrict__ w,
                                                 const float* __restrict__ stepp,
                                                 signed char* __restrict__ wq) {
  const int oc = blockIdx.x, tid = threadIdx.x;
  const float step = stepp[0];
  __shared__ __align__(16) signed char lds[9 * 128];
  for (int i = tid; i < 1152; i += 128) {
    const int c = i / 9, rs = i % 9;
    const float v = w[(size_t)(oc * C_IN + c) * 9 + rs];
    float t = 2.f * rintf(v / step + 0.5f) - 1.f;   // iw2 odd ints
    t = fminf(fmaxf(t, -3.f), 3.f);
    lds[rs * 128 + c] = (signed char)(int)t;
  }
  __syncthreads();
  for (int i = tid; i < 72; i += 128) {  // 9 rs * 8 uint4
    const int rs = i >> 3, c16 = i & 7;
    *(uint4*)(wq + ((size_t)(rs * 128 + oc)) * 128 + c16 * 16) = *(const uint4*)(lds + rs * 128 + c16 * 16);
  }
}

// ---------------- conv: block = 64 oc x 8 rows; 4 waves (one row-pair each) ----------------
// W staged once (72KB), act tile staged once (72.5KB), ONE barrier per block.
__global__ __launch_bounds__(256, 1) void conv_k(const signed char* __restrict__ apad,
                                                 const signed char* __restrict__ wq,
                                                 const float* __restrict__ stepp,
                                                 float* __restrict__ out) {
  __shared__ __align__(16) signed char Wl[9 * 64 * 128];    // 73728 B, XOR-swizzled
  __shared__ __align__(16) signed char Al[10 * 58 * 128];   // 74240 B, XOR-swizzled
  const int rg = blockIdx.x;   // 0..6 rowgroup (8 output rows)
  const int n = blockIdx.y;
  const int o2 = blockIdx.z;   // oc half
  const int tid = threadIdx.x;
  const int wv = tid >> 6, lane = tid & 63;
  const int lr = lane & 15, q4 = lane >> 4;

  // stage weights: 9 rs x 64 oc x 128 c = 4608 x 16B
  for (int i = tid; i < 4608; i += 256) {
    const int row = i >> 3, c16 = i & 7;         // row = rs*64 + ol
    const int rs = row >> 6, ol = row & 63;
    const uint4 v = *(const uint4*)(wq + ((size_t)(rs * 128 + o2 * 64 + ol)) * 128 + c16 * 16);
    *(uint4*)(Wl + ((row * 128 + c16 * 16) ^ ((row & 7) << 4))) = v;
  }
  // stage act tile: padded rows rg*8 .. rg*8+9, 10*58*128 = 4640 x 16B
  {
    const signed char* ag = apad + (size_t)n * APAD_NSTRIDE + (size_t)(rg * 8) * APAD_ROWSTRIDE;
    for (int i = tid; i < 4640; i += 256) {
      const int p = i >> 3, c16 = i & 7;
      const uint4 v = *(const uint4*)(ag + (size_t)p * 128 + c16 * 16);
      *(uint4*)(Al + ((p * 128 + c16 * 16) ^ ((p & 7) << 4))) = v;
    }
  }
  __syncthreads();

  // per-lane pixel base (r=0,s=0) for each of the 7 px fragments of this wave's row-pair
  int pbase[7];
#pragma unroll
  for (int pf = 0; pf < 7; ++pf) {
    const int po = pf * 16 + lr;                 // 0..111
    const int orow = wv * 2 + po / 56, ocol = po % 56;
    pbase[pf] = orow * 58 + ocol;
  }

  i32x4 acc[7][4];
#pragma unroll
  for (int i = 0; i < 7; ++i)
#pragma unroll
    for (int j = 0; j < 4; ++j) acc[i][j] = (i32x4){0, 0, 0, 0};

  const int kq = q4 * 16;  // K sub-chunk offset within 64
#pragma unroll
  for (int rs = 0; rs < 9; ++rs) {
    const int r = rs / 3, s = rs - 3 * r;
    const int poff = r * 58 + s;
#pragma unroll
    for (int k64 = 0; k64 < 2; ++k64) {
      const int kb = k64 * 64 + kq;
      i32x4 wf[4];
#pragma unroll
      for (int of = 0; of < 4; ++of) {
        const int row = rs * 64 + of * 16 + lr;
        wf[of] = *(const i32x4*)(Wl + ((row * 128 + kb) ^ ((row & 7) << 4)));
      }
#pragma unroll
      for (int pf = 0; pf < 7; ++pf) {
        const int p = pbase[pf] + poff;
        const i32x4 bf = *(const i32x4*)(Al + ((p * 128 + kb) ^ ((p & 7) << 4)));
        acc[pf][0] = __builtin_amdgcn_mfma_i32_16x16x64_i8(wf[0], bf, acc[pf][0], 0, 0, 0);
        acc[pf][1] = __builtin_amdgcn_mfma_i32_16x16x64_i8(wf[1], bf, acc[pf][1], 0, 0, 0);
        acc[pf][2] = __builtin_amdgcn_mfma_i32_16x16x64_i8(wf[2], bf, acc[pf][2], 0, 0, 0);
        acc[pf][3] = __builtin_amdgcn_mfma_i32_16x16x64_i8(wf[3], bf, acc[pf][3], 0, 0, 0);
      }
    }
  }

  const float oscale = 0.269f * stepp[0];  // a_step * w_step/2
  float* outn = out + (size_t)n * NPLANE;
#pragma unroll
  for (int pf = 0; pf < 7; ++pf) {
    const int po = pf * 16 + lr;
    const int h = rg * 8 + wv * 2 + po / 56, w_ = po % 56;
    float* op = outn + (size_t)h * HW + w_;
#pragma unroll
    for (int of = 0; of < 4; ++of) {
      const int oc = o2 * 64 + of * 16 + q4 * 4;
#pragma unroll
      for (int q = 0; q < 4; ++q)
        op[(size_t)(oc + q) * PIX] = (float)acc[pf][of][q] * oscale;
    }
  }
}

extern "C" void kernel_launch(void* const* d_in, const int* in_sizes, int n_in,
                              void* d_out, int out_size, void* d_ws, size_t ws_size,
                              hipStream_t stream) {
  const float* x = (const float*)d_in[0];
  const float* gamma = (const float*)d_in[1];
  const float* beta = (const float*)d_in[2];
  const float* w = (const float*)d_in[3];
  float* out = (float*)d_out;
  char* ws = (char*)d_ws;

  double* bnpart = (double*)(ws);                 // 16384 B
  double* wpart = (double*)(ws + 16384);          // 1024 B
  float2* affine = (float2*)(ws + 17408);         // 1024 B
  float* stepp = (float*)(ws + 18432);            // 4 B
  signed char* wq = (signed char*)(ws + 18688);   // 9*128*128 = 147456 B
  signed char* apad = (signed char*)(ws + 196608);// 32*58*58*128 = 13778944 B

  bn_partial_k<<<dim3(128, 8), 256, 0, stream>>>(x, bnpart);
  w_partial_k<<<64, 256, 0, stream>>>(w, wpart);
  finalize_k<<<1, 256, 0, stream>>>(bnpart, wpart, gamma, beta, affine, stepp);
  quant_act_k<<<dim3(58, 32), 256, 0, stream>>>(x, affine, apad);
  quant_w_k<<<128, 128, 0, stream>>>(w, stepp, wq);
  conv_k<<<dim3(7, 32, 2), 256, 0, stream>>>(apad, wq, stepp, out);
}

// Round 3
// 61.729 us; speedup vs baseline: 1.8779x; 1.2559x over previous
//
#include <hip/hip_runtime.h>

typedef int i32x4 __attribute__((ext_vector_type(4)));

#define C_IN 128
#define HW 56
#define PIX 3136            // 56*56
#define NPLANE 401408       // 128*3136
#define PROWB 7424          // 58*128 bytes per padded row (i8)
#define APAD_NSTRIDE 430592 // 58*58*128

// direct global->LDS DMA, 16B per lane, linear dest
static __device__ __forceinline__ void gload_lds16(const void* g, void* l) {
  __builtin_amdgcn_global_load_lds((__attribute__((address_space(1))) unsigned int*)g,
                                   (__attribute__((address_space(3))) unsigned int*)l, 16, 0, 0);
}

// ---------------- BN partial stats: grid (128 c, 8 slices) ----------------
__global__ __launch_bounds__(256) void bn_partial_k(const float* __restrict__ x,
                                                    double* __restrict__ part) {
  const int c = blockIdx.x, sl = blockIdx.y;
  const int tid = threadIdx.x;
  double s = 0.0, s2 = 0.0;
  for (int n = sl * 4; n < sl * 4 + 4; ++n) {
    const float4* p = (const float4*)(x + (size_t)(n * C_IN + c) * PIX);
    for (int i = tid; i < PIX / 4; i += 256) {
      float4 v = p[i];
      s  += (double)v.x + (double)v.y + (double)v.z + (double)v.w;
      s2 += (double)v.x * v.x + (double)v.y * v.y + (double)v.z * v.z + (double)v.w * v.w;
    }
  }
  __shared__ double red[8];
  const int lane = tid & 63, wv = tid >> 6;
  for (int off = 32; off; off >>= 1) { s += __shfl_down(s, off); s2 += __shfl_down(s2, off); }
  if (lane == 0) { red[wv * 2] = s; red[wv * 2 + 1] = s2; }
  __syncthreads();
  if (tid == 0) {
    part[(c * 8 + sl) * 2] = red[0] + red[2] + red[4] + red[6];
    part[(c * 8 + sl) * 2 + 1] = red[1] + red[3] + red[5] + red[7];
  }
}

// ---------------- weight partial stats ----------------
__global__ __launch_bounds__(256) void w_partial_k(const float* __restrict__ w,
                                                   double* __restrict__ part) {
  const int b = blockIdx.x, tid = threadIdx.x;
  double s = 0.0, s2 = 0.0;
  const float4* p = (const float4*)w;
  for (int i = b * 576 + tid; i < (b + 1) * 576; i += 256) {
    float4 v = p[i];
    s  += (double)v.x + (double)v.y + (double)v.z + (double)v.w;
    s2 += (double)v.x * v.x + (double)v.y * v.y + (double)v.z * v.z + (double)v.w * v.w;
  }
  __shared__ double red[8];
  const int lane = tid & 63, wv = tid >> 6;
  for (int off = 32; off; off >>= 1) { s += __shfl_down(s, off); s2 += __shfl_down(s2, off); }
  if (lane == 0) { red[wv * 2] = s; red[wv * 2 + 1] = s2; }
  __syncthreads();
  if (tid == 0) {
    part[b * 2] = red[0] + red[2] + red[4] + red[6];
    part[b * 2 + 1] = red[1] + red[3] + red[5] + red[7];
  }
}

// ---------------- quantize acts -> padded NHWC int8 levels, PRE-SWIZZLED ----------------
// byte layout within plane: (pp*128 + c) ^ ((pp&7)<<4), pp = padded pixel index.
__global__ __launch_bounds__(256) void quant_act_k(const float* __restrict__ x,
                                                   const double* __restrict__ bnpart,
                                                   const float* __restrict__ gamma,
                                                   const float* __restrict__ beta,
                                                   signed char* __restrict__ apad) {
  const int hh = blockIdx.x;  // padded row 0..57
  const int n = blockIdx.y;
  const int tid = threadIdx.x;
  __shared__ float2 aff[128];
  __shared__ __align__(16) signed char lds[58 * 144];
  if (tid < 128) {
    double s = 0.0, s2 = 0.0;
    for (int i = 0; i < 8; ++i) { s += bnpart[(tid * 8 + i) * 2]; s2 += bnpart[(tid * 8 + i) * 2 + 1]; }
    const double mean = s / 100352.0;
    const double var = s2 / 100352.0 - mean * mean;
    const double inv = 1.0 / sqrt(var + 1e-3);
    aff[tid] = make_float2((float)((double)gamma[tid] * inv),
                           (float)((double)beta[tid] - mean * inv * (double)gamma[tid]));
  }
  uint4* lds4 = (uint4*)lds;
  for (int i = tid; i < 58 * 144 / 16; i += 256) lds4[i] = make_uint4(0, 0, 0, 0);
  __syncthreads();
  if (hh >= 1 && hh <= 56) {
    const float* xp = x + (size_t)n * NPLANE + (hh - 1) * HW;
    for (int i = tid; i < C_IN * HW; i += 256) {
      const int w = i % HW, c = i / HW;
      const float v = xp[(size_t)c * PIX + w];
      const float2 af = aff[c];
      const float xn = fmaf(v, af.x, af.y);
      const float y = fminf(fmaxf(xn, 0.f), 1.614f);          // clip [0, 3*0.538]
      lds[(w + 1) * 144 + c] = (signed char)(int)rintf(y * (1.f / 0.538f));
    }
  }
  __syncthreads();
  signed char* dst = apad + (size_t)n * APAD_NSTRIDE;
  for (int i = tid; i < 58 * 8; i += 256) {
    const int col = i >> 3, c16 = i & 7;
    const int pp = hh * 58 + col;
    *(uint4*)(dst + (((size_t)pp * 128 + c16 * 16) ^ ((pp & 7) << 4))) = lds4[col * 9 + c16];
  }
}

// ---------------- quantize weights -> wq[rs][128 oc][128 c] int8, PRE-SWIZZLED ----------------
__global__ __launch_bounds__(128) void quant_w_k(const float* __restrict__ w,
                                                 const double* __restrict__ wpart,
                                                 signed char* __restrict__ wq,
                                                 float* __restrict__ stepp) {
  const int oc = blockIdx.x, tid = threadIdx.x;
  __shared__ float steps;
  __shared__ __align__(16) signed char lds[9 * 128];
  if (tid < 64) {
    double s = wpart[tid * 2], s2 = wpart[tid * 2 + 1];
    for (int off = 32; off; off >>= 1) { s += __shfl_down(s, off); s2 += __shfl_down(s2, off); }
    if (tid == 0) {
      const double mean = s / 147456.0;
      const double var = s2 / 147456.0 - mean * mean;
      steps = 0.996f * (float)sqrt(var);
      if (oc == 0) stepp[0] = steps;
    }
  }
  __syncthreads();
  const float step = steps;
  for (int i = tid; i < 1152; i += 128) {
    const int c = i / 9, rs = i % 9;
    const float v = w[(size_t)(oc * C_IN + c) * 9 + rs];
    float t = 2.f * rintf(v / step + 0.5f) - 1.f;  // iw2 odd ints
    t = fminf(fmaxf(t, -3.f), 3.f);
    lds[rs * 128 + c] = (signed char)(int)t;
  }
  __syncthreads();
  for (int i = tid; i < 72; i += 128) {
    const int rs = i >> 3, c16 = i & 7;
    *(uint4*)(wq + rs * 16384 + ((oc * 128 + c16 * 16) ^ ((oc & 7) << 4))) =
        *(const uint4*)(lds + rs * 128 + c16 * 16);
  }
}

// ---------------- conv: block = 128 oc x 224 px (4 rows); 4 waves; 2 blocks/CU ----------------
__global__ __launch_bounds__(256, 2) void conv_k(const signed char* __restrict__ apad,
                                                 const signed char* __restrict__ wq,
                                                 const float* __restrict__ stepp,
                                                 float* __restrict__ out) {
  __shared__ __align__(16) signed char Al[45056];      // 6 padded rows (44544B) + slack
  __shared__ __align__(16) signed char Wl[2][16384];   // per-rs weight panel, double-buffered
  const int rg = blockIdx.x;   // 0..13 (4-output-row groups)
  const int n = blockIdx.y;
  const int tid = threadIdx.x;
  const int wv = tid >> 6, lane = tid & 63;
  const int lr = lane & 15, q4 = lane >> 4;
  const int kq = q4 * 16;
  const int ohalf = (wv & 1) * 64;
  const int phalf = (wv >> 1) * 112;

  // issue act stage: 44 x 1KB (linear copy of pre-swizzled bytes)
  {
    const signed char* gsrc = apad + (size_t)n * APAD_NSTRIDE + (size_t)(rg * 4) * PROWB;
    for (int i = wv; i < 44; i += 4)
      gload_lds16(gsrc + i * 1024 + lane * 16, Al + i * 1024);
  }
  // issue W[rs=0]
  for (int i = wv; i < 16; i += 4)
    gload_lds16(wq + i * 1024 + lane * 16, &Wl[0][i * 1024]);

  int pbase[7];
#pragma unroll
  for (int pf = 0; pf < 7; ++pf) {
    const int po = phalf + pf * 16 + lr;   // 0..223
    pbase[7 > pf ? pf : 0] = (po / 56) * 58 + po % 56;
  }

  i32x4 acc[7][4];
#pragma unroll
  for (int i = 0; i < 7; ++i)
#pragma unroll
    for (int j = 0; j < 4; ++j) acc[i][j] = (i32x4){0, 0, 0, 0};

  __syncthreads();  // drains all staging loads

  for (int rs = 0; rs < 9; ++rs) {
    if (rs < 8) {  // prefetch next weight panel; lands before next barrier
      for (int i = wv; i < 16; i += 4)
        gload_lds16(wq + (rs + 1) * 16384 + i * 1024 + lane * 16, &Wl[(rs + 1) & 1][i * 1024]);
    }
    const int r = rs / 3, s = rs - 3 * r;
    const int poff = r * 58 + s;
    const signed char* Wb = Wl[rs & 1];
#pragma unroll
    for (int k64 = 0; k64 < 2; ++k64) {
      const int kb = k64 * 64 + kq;
      i32x4 wf[4];
#pragma unroll
      for (int of = 0; of < 4; ++of) {
        const int row = ohalf + of * 16 + lr;
        wf[of] = *(const i32x4*)(Wb + row * 128 + (kb ^ ((row & 7) << 4)));
      }
#pragma unroll
      for (int pf = 0; pf < 7; ++pf) {
        const int p = pbase[pf] + poff;
        const i32x4 bf = *(const i32x4*)(Al + p * 128 + (kb ^ ((p & 7) << 4)));
        acc[pf][0] = __builtin_amdgcn_mfma_i32_16x16x64_i8(wf[0], bf, acc[pf][0], 0, 0, 0);
        acc[pf][1] = __builtin_amdgcn_mfma_i32_16x16x64_i8(wf[1], bf, acc[pf][1], 0, 0, 0);
        acc[pf][2] = __builtin_amdgcn_mfma_i32_16x16x64_i8(wf[2], bf, acc[pf][2], 0, 0, 0);
        acc[pf][3] = __builtin_amdgcn_mfma_i32_16x16x64_i8(wf[3], bf, acc[pf][3], 0, 0, 0);
      }
    }
    __syncthreads();  // all waves done with Wb; next panel landed
  }

  const float oscale = 0.269f * stepp[0];  // a_step * w_step/2
  float* outn = out + (size_t)n * NPLANE + (size_t)rg * 224;  // 4-row slab base
#pragma unroll
  for (int pf = 0; pf < 7; ++pf) {
    const int po = phalf + pf * 16 + lr;  // offset within slab = row*56+col = po
    float* op = outn + po;
#pragma unroll
    for (int of = 0; of < 4; ++of) {
      const int oc = ohalf + of * 16 + q4 * 4;
#pragma unroll
      for (int q = 0; q < 4; ++q)
        op[(size_t)(oc + q) * PIX] = (float)acc[pf][of][q] * oscale;
    }
  }
}

extern "C" void kernel_launch(void* const* d_in, const int* in_sizes, int n_in,
                              void* d_out, int out_size, void* d_ws, size_t ws_size,
                              hipStream_t stream) {
  const float* x = (const float*)d_in[0];
  const float* gamma = (const float*)d_in[1];
  const float* beta = (const float*)d_in[2];
  const float* w = (const float*)d_in[3];
  float* out = (float*)d_out;
  char* ws = (char*)d_ws;

  double* bnpart = (double*)(ws);                  // 16384 B
  double* wpart = (double*)(ws + 16384);           // 1024 B
  float* stepp = (float*)(ws + 17408);             // 4 B (pad to 1KB)
  signed char* wq = (signed char*)(ws + 18432);    // 9*128*128 = 147456 B -> ends 165888
  signed char* apad = (signed char*)(ws + 196608); // 32*58*58*128 = 13778944 B + 1KB slack

  bn_partial_k<<<dim3(128, 8), 256, 0, stream>>>(x, bnpart);
  w_partial_k<<<64, 256, 0, stream>>>(w, wpart);
  quant_act_k<<<dim3(58, 32), 256, 0, stream>>>(x, bnpart, gamma, beta, apad);
  quant_w_k<<<128, 128, 0, stream>>>(w, wpart, wq, stepp);
  conv_k<<<dim3(14, 32), 256, 0, stream>>>(apad, wq, stepp, out);
}

// Round 6
// 52.844 us; speedup vs baseline: 2.1936x; 1.1681x over previous
//
#include <hip/hip_runtime.h>

typedef int i32x4 __attribute__((ext_vector_type(4)));

#define C_IN 128
#define HW 56
#define PIX 3136            // 56*56
#define NPLANE 401408       // 128*3136
#define PROWB 7424          // 58*128 bytes per padded row (i8)
#define APAD_NSTRIDE 430592 // 58*58*128

// direct global->LDS DMA, 16B per lane, linear dest
static __device__ __forceinline__ void gload_lds16(const void* g, void* l) {
  __builtin_amdgcn_global_load_lds((__attribute__((address_space(1))) unsigned int*)g,
                                   (__attribute__((address_space(3))) unsigned int*)l, 16, 0, 0);
}

// ---------------- fused stats: blocks 0..1023 = BN (c,slice), 1024..1087 = weight chunks ----------------
__global__ __launch_bounds__(256) void stats_k(const float* __restrict__ x,
                                               const float* __restrict__ w,
                                               double* __restrict__ bnpart,
                                               double* __restrict__ wpart) {
  const int b = blockIdx.x, tid = threadIdx.x;
  double s = 0.0, s2 = 0.0;
  if (b < 1024) {
    const int c = b & 127, sl = b >> 7;
    for (int n = sl * 4; n < sl * 4 + 4; ++n) {
      const float4* p = (const float4*)(x + (size_t)(n * C_IN + c) * PIX);
      for (int i = tid; i < PIX / 4; i += 256) {
        float4 v = p[i];
        s  += (double)v.x + (double)v.y + (double)v.z + (double)v.w;
        s2 += (double)v.x * v.x + (double)v.y * v.y + (double)v.z * v.z + (double)v.w * v.w;
      }
    }
  } else {
    const int wb = b - 1024;
    const float4* p = (const float4*)w;
    for (int i = wb * 576 + tid; i < (wb + 1) * 576; i += 256) {
      float4 v = p[i];
      s  += (double)v.x + (double)v.y + (double)v.z + (double)v.w;
      s2 += (double)v.x * v.x + (double)v.y * v.y + (double)v.z * v.z + (double)v.w * v.w;
    }
  }
  __shared__ double red[8];
  const int lane = tid & 63, wv = tid >> 6;
  for (int off = 32; off; off >>= 1) { s += __shfl_down(s, off); s2 += __shfl_down(s2, off); }
  if (lane == 0) { red[wv * 2] = s; red[wv * 2 + 1] = s2; }
  __syncthreads();
  if (tid == 0) {
    // bnpart layout must be [c][sl] (consumer reads c*8+sl)
    double* dst = (b < 1024) ? (bnpart + ((b & 127) * 8 + (b >> 7)) * 2)
                             : (wpart + (b - 1024) * 2);
    dst[0] = red[0] + red[2] + red[4] + red[6];
    dst[1] = red[1] + red[3] + red[5] + red[7];
  }
}

// ---------------- fused quantize: y<32 = act rows (pre-swizzled apad), y==32 = weights ----------------
__global__ __launch_bounds__(256) void quant_k(const float* __restrict__ x,
                                               const float* __restrict__ w,
                                               const float* __restrict__ gamma,
                                               const float* __restrict__ beta,
                                               const double* __restrict__ bnpart,
                                               const double* __restrict__ wpart,
                                               signed char* __restrict__ apad,
                                               signed char* __restrict__ wq,
                                               float* __restrict__ stepp) {
  const int tid = threadIdx.x;
  if (blockIdx.y == 32) {
    // ---- weight path: block bx handles oc in {bx, bx+58, bx+116} ----
    const int bx = blockIdx.x;
    __shared__ float steps;
    __shared__ __align__(16) signed char wl[3 * 1152];   // [oi][rs][c] layout
    if (tid < 64) {
      double s = wpart[tid * 2], s2 = wpart[tid * 2 + 1];
      for (int off = 32; off; off >>= 1) { s += __shfl_down(s, off); s2 += __shfl_down(s2, off); }
      if (tid == 0) {
        const double mean = s / 147456.0;
        const double var = s2 / 147456.0 - mean * mean;
        steps = 0.996f * (float)sqrt(var);
        if (bx == 0) stepp[0] = steps;
      }
    }
    __syncthreads();
    const float step = steps;
    for (int i = tid; i < 3456; i += 256) {
      const int oi = i / 1152, rem = i - oi * 1152;
      const int oc = bx + oi * 58;
      if (oc < 128) {
        const int c = rem / 9, rs = rem - c * 9;
        const float v = w[(size_t)(oc * C_IN + c) * 9 + rs];
        float t = 2.f * rintf(v / step + 0.5f) - 1.f;  // iw2 odd ints
        t = fminf(fmaxf(t, -3.f), 3.f);
        wl[oi * 1152 + rs * 128 + c] = (signed char)(int)t;   // [rs][c] layout
      }
    }
    __syncthreads();
    for (int i = tid; i < 216; i += 256) {  // 3 oc * 9 rs * 8 uint4
      const int oi = i / 72, rem = i - oi * 72;
      const int oc = bx + oi * 58;
      if (oc < 128) {
        const int rs = rem >> 3, c16 = rem & 7;
        *(uint4*)(wq + rs * 16384 + ((oc * 128 + c16 * 16) ^ ((oc & 7) << 4))) =
            *(const uint4*)(wl + oi * 1152 + rs * 128 + c16 * 16);
      }
    }
    return;
  }
  // ---- act path: padded row hh of image n ----
  const int hh = blockIdx.x;
  const int n = blockIdx.y;
  __shared__ float2 aff[128];
  __shared__ __align__(16) signed char lds[58 * 144];
  if (tid < 128) {
    double s = 0.0, s2 = 0.0;
    for (int i = 0; i < 8; ++i) { s += bnpart[(tid * 8 + i) * 2]; s2 += bnpart[(tid * 8 + i) * 2 + 1]; }
    const double mean = s / 100352.0;
    const double var = s2 / 100352.0 - mean * mean;
    const double inv = 1.0 / sqrt(var + 1e-3);
    aff[tid] = make_float2((float)((double)gamma[tid] * inv),
                           (float)((double)beta[tid] - mean * inv * (double)gamma[tid]));
  }
  uint4* lds4 = (uint4*)lds;
  for (int i = tid; i < 58 * 144 / 16; i += 256) lds4[i] = make_uint4(0, 0, 0, 0);
  __syncthreads();
  if (hh >= 1 && hh <= 56) {
    const float* xp = x + (size_t)n * NPLANE + (hh - 1) * HW;
    for (int i = tid; i < C_IN * HW; i += 256) {
      const int ww = i % HW, c = i / HW;
      const float v = xp[(size_t)c * PIX + ww];
      const float2 af = aff[c];
      const float xn = fmaf(v, af.x, af.y);
      const float y = fminf(fmaxf(xn, 0.f), 1.614f);          // clip [0, 3*0.538]
      lds[(ww + 1) * 144 + c] = (signed char)(int)rintf(y * (1.f / 0.538f));
    }
  }
  __syncthreads();
  signed char* dst = apad + (size_t)n * APAD_NSTRIDE;
  for (int i = tid; i < 58 * 8; i += 256) {
    const int col = i >> 3, c16 = i & 7;
    const int pp = hh * 58 + col;
    *(uint4*)(dst + (((size_t)pp * 128 + c16 * 16) ^ ((pp & 7) << 4))) = lds4[col * 9 + c16];
  }
}

// ---------------- conv: block = 128 oc x 224 px (4 rows); 4 waves; 2 blocks/CU ----------------
__global__ __launch_bounds__(256, 2) void conv_k(const signed char* __restrict__ apad,
                                                 const signed char* __restrict__ wq,
                                                 const float* __restrict__ stepp,
                                                 float* __restrict__ out) {
  __shared__ __align__(16) signed char Al[45056];      // 6 padded rows (44544B) + slack
  __shared__ __align__(16) signed char Wl[2][16384];   // per-rs weight panel, double-buffered
  // XCD-bijective swizzle: 448 blocks = 8 XCDs x 56; consecutive vid (same n, adjacent rg)
  // share halo rows + wq panels in one XCD's L2.
  const int bid = blockIdx.x;
  const int vid = (bid & 7) * 56 + (bid >> 3);
  const int n = vid / 14;
  const int rg = vid - n * 14;
  const int tid = threadIdx.x;
  const int wv = tid >> 6, lane = tid & 63;
  const int lr = lane & 15, q4 = lane >> 4;
  const int kq = q4 * 16;
  const int ohalf = (wv & 1) * 64;
  const int phalf = (wv >> 1) * 112;

  // issue act stage: 44 x 1KB (linear copy of pre-swizzled bytes)
  {
    const signed char* gsrc = apad + (size_t)n * APAD_NSTRIDE + (size_t)(rg * 4) * PROWB;
    for (int i = wv; i < 44; i += 4)
      gload_lds16(gsrc + i * 1024 + lane * 16, Al + i * 1024);
  }
  // issue W[rs=0]
  for (int i = wv; i < 16; i += 4)
    gload_lds16(wq + i * 1024 + lane * 16, &Wl[0][i * 1024]);

  int pbase[7];
#pragma unroll
  for (int pf = 0; pf < 7; ++pf) {
    const int po = phalf + pf * 16 + lr;   // 0..223
    pbase[pf] = (po / 56) * 58 + po % 56;
  }

  i32x4 acc[7][4];
#pragma unroll
  for (int i = 0; i < 7; ++i)
#pragma unroll
    for (int j = 0; j < 4; ++j) acc[i][j] = (i32x4){0, 0, 0, 0};

  __syncthreads();  // drains all staging loads

  for (int rs = 0; rs < 9; ++rs) {
    if (rs < 8) {  // prefetch next weight panel; lands before next barrier
      for (int i = wv; i < 16; i += 4)
        gload_lds16(wq + (rs + 1) * 16384 + i * 1024 + lane * 16, &Wl[(rs + 1) & 1][i * 1024]);
    }
    const int r = rs / 3, s = rs - 3 * r;
    const int poff = r * 58 + s;
    const signed char* Wb = Wl[rs & 1];
#pragma unroll
    for (int k64 = 0; k64 < 2; ++k64) {
      const int kb = k64 * 64 + kq;
      i32x4 wf[4];
#pragma unroll
      for (int of = 0; of < 4; ++of) {
        const int row = ohalf + of * 16 + lr;
        wf[of] = *(const i32x4*)(Wb + row * 128 + (kb ^ ((row & 7) << 4)));
      }
#pragma unroll
      for (int pf = 0; pf < 7; ++pf) {
        const int p = pbase[pf] + poff;
        const i32x4 bf = *(const i32x4*)(Al + p * 128 + (kb ^ ((p & 7) << 4)));
        acc[pf][0] = __builtin_amdgcn_mfma_i32_16x16x64_i8(wf[0], bf, acc[pf][0], 0, 0, 0);
        acc[pf][1] = __builtin_amdgcn_mfma_i32_16x16x64_i8(wf[1], bf, acc[pf][1], 0, 0, 0);
        acc[pf][2] = __builtin_amdgcn_mfma_i32_16x16x64_i8(wf[2], bf, acc[pf][2], 0, 0, 0);
        acc[pf][3] = __builtin_amdgcn_mfma_i32_16x16x64_i8(wf[3], bf, acc[pf][3], 0, 0, 0);
      }
    }
    if (rs < 8) __syncthreads();  // all waves done with Wb; next panel landed
  }

  const float oscale = 0.269f * stepp[0];  // a_step * w_step/2
  float* outn = out + (size_t)n * NPLANE + (size_t)rg * 224;  // 4-row slab base
#pragma unroll
  for (int pf = 0; pf < 7; ++pf) {
    const int po = phalf + pf * 16 + lr;  // offset within slab = row*56+col
    float* op = outn + po;
#pragma unroll
    for (int of = 0; of < 4; ++of) {
      const int oc = ohalf + of * 16 + q4 * 4;
#pragma unroll
      for (int q = 0; q < 4; ++q)
        op[(size_t)(oc + q) * PIX] = (float)acc[pf][of][q] * oscale;
    }
  }
}

extern "C" void kernel_launch(void* const* d_in, const int* in_sizes, int n_in,
                              void* d_out, int out_size, void* d_ws, size_t ws_size,
                              hipStream_t stream) {
  const float* x = (const float*)d_in[0];
  const float* gamma = (const float*)d_in[1];
  const float* beta = (const float*)d_in[2];
  const float* w = (const float*)d_in[3];
  float* out = (float*)d_out;
  char* ws = (char*)d_ws;

  double* bnpart = (double*)(ws);                  // 16384 B
  double* wpart = (double*)(ws + 16384);           // 1024 B
  float* stepp = (float*)(ws + 17408);             // 4 B (pad to 1KB)
  signed char* wq = (signed char*)(ws + 18432);    // 9*128*128 = 147456 B -> ends 165888
  signed char* apad = (signed char*)(ws + 196608); // 32*58*58*128 = 13778944 B + slack

  stats_k<<<1088, 256, 0, stream>>>(x, w, bnpart, wpart);
  quant_k<<<dim3(58, 33), 256, 0, stream>>>(x, w, gamma, beta, bnpart, wpart, apad, wq, stepp);
  conv_k<<<448, 256, 0, stream>>>(apad, wq, stepp, out);
}